// Round 9
// baseline (1263.177 us; speedup 1.0000x reference)
//
#include <hip/hip_runtime.h>
#include <math.h>

#define BZ 32
#define FCH 160
#define NMIX 10
#define PCH 100

typedef __attribute__((ext_vector_type(8))) short bf16x8;
typedef __attribute__((ext_vector_type(8))) unsigned short u16x8;
typedef __attribute__((ext_vector_type(4))) unsigned short u16x4;
typedef __attribute__((ext_vector_type(4))) float f32x4;

__device__ __forceinline__ unsigned short f2bf(float f) {
    union { float f; unsigned u; } x; x.f = f;
    return (unsigned short)((x.u + 0x7FFFu + ((x.u >> 16) & 1u)) >> 16);
}
__device__ __forceinline__ void elupair(float v, float& e0, float& e1) {
    if (v > 0.f) { e0 = v; e1 = expm1f(-v); }
    else         { e0 = expm1f(v); e1 = -v; }
}
// LDS swizzle (read side): row p of 32 halfwords, 4 segs of 8hw (16B).
// slot = seg ^ f(p). Staging writes are linear (global_load_lds: lane*16B);
// the swizzle is applied on the SOURCE address (seg_src = (lane&3) ^ f(row)).
__device__ __forceinline__ int fsw(int p) { return (p + (p >> 2)) & 3; }
__device__ __forceinline__ int swz(int p, int seg) {
    return p * 32 + ((seg ^ fsw(p)) << 3);
}
__device__ __forceinline__ void load_lds16(const unsigned short* g, unsigned short* l) {
    __builtin_amdgcn_global_load_lds(
        (const __attribute__((address_space(1))) unsigned int*)g,
        (__attribute__((address_space(3))) unsigned int*)l, 16, 0, 0);
}

// ---------------------------------------------------------------------------
// Weight repack: w[NB][Cout][Cin][NT] fp32 -> wb[NB][CoutPad][NT][Cin] bf16,
// optional concat-elu K interleave. Block per (nb,o): coalesced LDS transpose.
// ---------------------------------------------------------------------------
__global__ __launch_bounds__(256) void repack_k(
    const float* __restrict__ w, unsigned short* __restrict__ wb,
    int Cout, int Cin, int NT, int ILV)
{
    __shared__ float ws[1920];
    const int o = blockIdx.x;            // < CoutPad
    const int nb = blockIdx.y;
    const int CoutPad = gridDim.x;
    const int n = Cin * NT;
    unsigned short* dst = wb + (size_t)(nb * CoutPad + o) * n;
    if (o >= Cout) {
        for (int e = threadIdx.x; e < n; e += 256) dst[e] = 0;
        return;
    }
    const float* src = w + (size_t)(nb * Cout + o) * n;
    for (int e = threadIdx.x; e < n; e += 256) ws[e] = src[e];
    __syncthreads();
    const int half = Cin >> 1;
    for (int e = threadIdx.x; e < n; e += 256) {
        int tap = e / Cin;
        int k = e - tap * Cin;
        int csrc = ILV ? ((k & 1) ? (half + (k >> 1)) : (k >> 1)) : k;
        dst[e] = f2bf(ws[csrc * NT + tap]);
    }
}

// ---------------------------------------------------------------------------
// Fused init convs: one block per (row i, batch b). Block (0,0) also zeroes
// the conv guard buffer.
// ---------------------------------------------------------------------------
__global__ __launch_bounds__(256) void init_both_k(
    const float* __restrict__ smp,
    const float* __restrict__ wu_g, const float* __restrict__ bu_g,
    const float* __restrict__ wd_g, const float* __restrict__ bd_g,
    const float* __restrict__ wr_g, const float* __restrict__ br_g,
    float* __restrict__ u, float* __restrict__ ul,
    unsigned short* __restrict__ ceu, unsigned short* __restrict__ ceul,
    float* __restrict__ zg)
{
    __shared__ float wU[160 * 24];
    __shared__ float wD[160 * 12];
    __shared__ float wR[160 * 8];
    __shared__ float bU[160], bD[160], bR[160];
    __shared__ float X[3][4][34];

    const int tid = threadIdx.x;
    const int i = blockIdx.x;
    const int b = blockIdx.y;

    if (i == 0 && b == 0 && tid < 128) {
        f32x4 z = {0.f, 0.f, 0.f, 0.f};
        ((f32x4*)zg)[tid] = z;
    }

    for (int e = tid; e < 160 * 24; e += 256) wU[e] = wu_g[e];
    for (int e = tid; e < 160 * 12; e += 256) wD[e] = wd_g[e];
    for (int e = tid; e < 160 * 8;  e += 256) wR[e] = wr_g[e];
    if (tid < 160) { bU[tid] = bu_g[tid]; bD[tid] = bd_g[tid]; bR[tid] = br_g[tid]; }
    for (int e = tid; e < 3 * 4 * 34; e += 256) {
        int col = e % 34;
        int c = (e / 34) & 3;
        int rs = e / (34 * 4);
        int r = i - 2 + rs;
        int jj = col - 1;
        float v = 0.f;
        if ((unsigned)r < 32u && (unsigned)jj < 32u)
            v = (c < 3) ? (smp[(((size_t)b * 3 + c) << 10) + (r << 5) + jj] * 2.f - 1.f)
                        : 1.f;
        X[rs][c][col] = v;
    }
    __syncthreads();
    if (tid >= 160) return;
    const int o = tid;

    float wu_r[24], wd_r[12], wr_r[8];
#pragma unroll
    for (int q = 0; q < 24; ++q) wu_r[q] = wU[o * 24 + q];
#pragma unroll
    for (int q = 0; q < 12; ++q) wd_r[q] = wD[o * 12 + q];
#pragma unroll
    for (int q = 0; q < 8; ++q)  wr_r[q] = wR[o * 8 + q];
    const float bu_v = (i > 0) ? bU[o] : 0.f;
    const float bd_v = (i >= 1) ? bD[o] : 0.f;
    const float br_v = bR[o];

    for (int j = 0; j < 32; ++j) {
        float su = 0.f, sd = 0.f, sr = 0.f;
#pragma unroll
        for (int c = 0; c < 4; ++c) {
            float x00 = X[0][c][j], x01 = X[0][c][j + 1], x02 = X[0][c][j + 2];
            float x10 = X[1][c][j], x11 = X[1][c][j + 1], x12 = X[1][c][j + 2];
            float x20 = X[2][c][j];
            su += wu_r[c * 6 + 0] * x00 + wu_r[c * 6 + 1] * x01 + wu_r[c * 6 + 2] * x02
                + wu_r[c * 6 + 3] * x10 + wu_r[c * 6 + 4] * x11 + wu_r[c * 6 + 5] * x12;
            sd += wd_r[c * 3 + 0] * x10 + wd_r[c * 3 + 1] * x11 + wd_r[c * 3 + 2] * x12;
            sr += wr_r[c * 2 + 0] * x10 + wr_r[c * 2 + 1] * x20;
        }
        float uv = (i > 0) ? (su + bu_v) : 0.f;
        float ulv = sd + bd_v + sr + ((j >= 1) ? br_v : 0.f);

        size_t base = (size_t)((b << 10) | (i << 5) | j);
        u[base * 160 + o] = uv;
        ul[base * 160 + o] = ulv;
        float e0, e1;
        elupair(uv, e0, e1);
        unsigned pu = (unsigned)f2bf(e0) | ((unsigned)f2bf(e1) << 16);
        *(unsigned*)(ceu + base * 320 + 2 * o) = pu;
        elupair(ulv, e0, e1);
        unsigned pl = (unsigned)f2bf(e0) | ((unsigned)f2bf(e1) << 16);
        *(unsigned*)(ceul + base * 320 + 2 * o) = pl;
    }
}

// ---------------------------------------------------------------------------
// MFMA implicit-GEMM conv, channel-last activations [b][pix][320].
// XCD-aware 1D block swizzle (FETCH 75->31MB). Per-variant schedule:
//  DBUF=1 (fits 2 blocks/CU): double-buffered LDS, stage(ci+1) issued before
//    compute(ci), ONE barrier/chunk -> DMA latency hidden under compute AND
//    2-block TLP. (r7 overlap + r8 residency, combined.)
//  DBUF=0 (u_c2, 44.5KB/buf): single buffer, 3 blocks/CU, 2 barriers/chunk.
// ---------------------------------------------------------------------------
template<int KH, int KW, int PT, int PL, bool DUAL, bool GATE, int MBLK, bool DBUF>
__global__ __launch_bounds__(256) void conv_mfma_k(
    const unsigned short* __restrict__ cein,
    const unsigned short* __restrict__ wb,
    const unsigned short* __restrict__ cein2,
    const unsigned short* __restrict__ wb2,
    const float* __restrict__ bias, const float* __restrict__ bias2,
    float* __restrict__ resid,
    unsigned short* __restrict__ ceout,
    const unsigned short* __restrict__ zguard)
{
    constexpr int NT = KH * KW;
    constexpr int RW = 8 + KH - 1;                  // 9
    constexpr int CW = 32 + KW - 1;                 // 33/34
    constexpr int MTILES = MBLK / 16;
    constexpr int MSH = (MBLK == 32) ? 5 : 6;
    constexpr int NSA = NT * MBLK / 64;
    constexpr int NSB = (RW * CW * 4 + 255) / 256;  // 5
    constexpr int NBUF = DBUF ? 2 : 1;
    constexpr int BSZ = NSB * 64 * 32;
    constexpr int WSZ = NT * MBLK * 32;

    __shared__ __align__(16) unsigned short bs[NBUF][BSZ];
    __shared__ __align__(16) unsigned short wsm[NBUF][WSZ];

    const int tid = threadIdx.x;
    const int wv = tid >> 6;
    const int lane = tid & 63;
    const int l16 = lane & 15;
    const int quad = lane >> 4;

    // XCD-aware decode (grid = 640 = 8 XCDs * 16 ytiles * 5 mtiles)
    const int bid = blockIdx.x;
    const int q8 = bid >> 3;
    const int yt = (bid & 7) * 16 + q8 / 5;         // pixel tile 0..127
    const int m0 = (q8 % 5) * 32;
    const int bimg = yt >> 2;
    const int rowbase = (yt & 3) * 8;

    const int sd = lane & 3;        // dest seg slot (linear DMA)
    const int lr = lane >> 2;       // row-within-16

    // ---- per-lane staging sources, computed ONCE (ci*32 added per chunk)
    const unsigned short* srcA[NSA];
#pragma unroll
    for (int it = 0; it < NSA; ++it) {
        int row = it * 64 + wv * 16 + lr;           // = tap*MBLK + mm
        int tap = row >> MSH;
        int mm = row & (MBLK - 1);
        int o = GATE ? (mm < 32 ? m0 + mm : 128 + m0 + mm) : (m0 + mm);
        int ss = sd ^ fsw(row);
        srcA[it] = wb + ((size_t)o * NT + tap) * 320 + ss * 8;
    }
    const unsigned short* srcB[NSB];
#pragma unroll
    for (int it = 0; it < NSB; ++it) {
        int p = it * 64 + wv * 16 + lr;
        int r = p / CW;
        int c = p - r * CW;
        int grow = rowbase + r - PT;
        int gcol = c - PL;
        int ss = sd ^ fsw(p);
        bool ok = (p < RW * CW) && ((unsigned)grow < 32u) && ((unsigned)gcol < 32u);
        srcB[it] = ok ? cein + (size_t)(((bimg << 10) | (grow << 5) | gcol)) * 320 + ss * 8
                      : zguard;
    }

    f32x4 acc[MTILES][4];
#pragma unroll
    for (int mt = 0; mt < MTILES; ++mt)
#pragma unroll
        for (int ng = 0; ng < 4; ++ng)
#pragma unroll
            for (int r = 0; r < 4; ++r) acc[mt][ng][r] = 0.f;

    auto STAGE = [&](int ci, int bi) {
#pragma unroll
        for (int it = 0; it < NSB; ++it)
            load_lds16(srcB[it] + ci * 32, &bs[bi][(it * 64 + wv * 16) * 32]);
#pragma unroll
        for (int it = 0; it < NSA; ++it)
            load_lds16(srcA[it] + ci * 32, &wsm[bi][(it * 64 + wv * 16) * 32]);
    };
    auto COMPUTE = [&](int bi) {
#pragma unroll
        for (int tap = 0; tap < NT; ++tap) {
            const int kh = tap / KW, kw = tap % KW;
            bf16x8 af[MTILES];
#pragma unroll
            for (int mt = 0; mt < MTILES; ++mt)
                af[mt] = *(const bf16x8*)&wsm[bi][swz(tap * MBLK + mt * 16 + l16, quad)];
#pragma unroll
            for (int ng = 0; ng < 4; ++ng) {
                int rl = 2 * wv + (ng >> 1) + kh;
                int cc = (ng & 1) * 16 + l16 + kw;
                bf16x8 bfr = *(const bf16x8*)&bs[bi][swz(rl * CW + cc, quad)];
#pragma unroll
                for (int mt = 0; mt < MTILES; ++mt)
                    acc[mt][ng] = __builtin_amdgcn_mfma_f32_16x16x32_bf16(af[mt], bfr, acc[mt][ng], 0, 0, 0);
            }
        }
    };

    if (DBUF) {
        STAGE(0, 0);
        __syncthreads();                     // drain prologue DMA
        for (int ci = 0; ci < 10; ++ci) {
            if (ci < 9) STAGE(ci + 1, (ci + 1) & 1);  // flies during compute
            COMPUTE(ci & 1);
            __syncthreads();                 // drains next-chunk DMA (overlapped)
        }
    } else {
        for (int ci = 0; ci < 10; ++ci) {
            __syncthreads();                 // previous compute done reading LDS
            STAGE(ci, 0);
            __syncthreads();                 // drains vmcnt -> LDS ready
            COMPUTE(0);
        }
    }

    if (DUAL) {  // fused 1x1 nin over second CE input (MBLK==32 path)
        const unsigned short* srcB2[4];
#pragma unroll
        for (int it = 0; it < 4; ++it) {
            int p2 = it * 64 + wv * 16 + lr;
            int r = p2 >> 5, c = p2 & 31;
            int ss = sd ^ fsw(p2);
            srcB2[it] = cein2 + (size_t)(((bimg << 10) | ((rowbase + r) << 5) | c)) * 320 + ss * 8;
        }
        int row2 = wv * 16 + lr;                    // valid for wv<2
        int mm2 = row2 & 31;
        const unsigned short* srcA2 =
            wb2 + (size_t)(m0 + mm2) * 320 + (sd ^ fsw(row2)) * 8;

        auto STAGE2 = [&](int ci, int bi) {
#pragma unroll
            for (int it = 0; it < 4; ++it)
                load_lds16(srcB2[it] + ci * 32, &bs[bi][(it * 64 + wv * 16) * 32]);
            if (wv < 2)
                load_lds16(srcA2 + ci * 32, &wsm[bi][(wv * 16) * 32]);
        };
        auto COMPUTE2 = [&](int bi) {
            bf16x8 af[MTILES];
#pragma unroll
            for (int mt = 0; mt < MTILES; ++mt)
                af[mt] = *(const bf16x8*)&wsm[bi][swz(mt * 16 + l16, quad)];
#pragma unroll
            for (int ng = 0; ng < 4; ++ng) {
                int rl = 2 * wv + (ng >> 1);
                int cc = (ng & 1) * 16 + l16;
                bf16x8 bfr = *(const bf16x8*)&bs[bi][swz(rl * 32 + cc, quad)];
#pragma unroll
                for (int mt = 0; mt < MTILES; ++mt)
                    acc[mt][ng] = __builtin_amdgcn_mfma_f32_16x16x32_bf16(af[mt], bfr, acc[mt][ng], 0, 0, 0);
            }
        };

        if (DBUF) {
            STAGE2(0, 0);
            __syncthreads();
            for (int ci = 0; ci < 10; ++ci) {
                if (ci < 9) STAGE2(ci + 1, (ci + 1) & 1);
                COMPUTE2(ci & 1);
                __syncthreads();
            }
        } else {
            for (int ci = 0; ci < 10; ++ci) {
                __syncthreads();
                STAGE2(ci, 0);
                __syncthreads();
                COMPUTE2(0);
            }
        }
    }

    // ---- epilogue (vectorized channel-last stores)
    constexpr int MOUT = GATE ? MTILES / 2 : MTILES;
#pragma unroll
    for (int mt = 0; mt < MOUT; ++mt) {
        int ob = m0 + mt * 16 + quad * 4;
        f32x4 bv = *(const f32x4*)(bias + ob);
        f32x4 bv2;
        if (DUAL) bv2 = *(const f32x4*)(bias2 + ob);
        f32x4 bg;
        if (GATE) bg = *(const f32x4*)(bias + ob + 160);
#pragma unroll
        for (int ng = 0; ng < 4; ++ng) {
            int i = rowbase + 2 * wv + (ng >> 1);
            int j = (ng & 1) * 16 + l16;
            size_t pb = (size_t)((bimg << 10) | (i << 5) | j);
            if (!GATE) {
                u16x8 st;
#pragma unroll
                for (int r = 0; r < 4; ++r) {
                    float v = acc[mt][ng][r] + bv[r] + (DUAL ? bv2[r] : 0.f);
                    float e0, e1; elupair(v, e0, e1);
                    st[2 * r] = f2bf(e0); st[2 * r + 1] = f2bf(e1);
                }
                *(u16x8*)(ceout + pb * 320 + 2 * ob) = st;
            } else {
                f32x4 rv = *(const f32x4*)(resid + pb * 160 + ob);
                u16x8 st;
#pragma unroll
                for (int r = 0; r < 4; ++r) {
                    float g1 = acc[mt][ng][r] + bv[r];
                    float g2 = acc[mt + MTILES / 2][ng][r] + bg[r];
                    float v = rv[r] + g1 / (1.f + expf(-g2));
                    rv[r] = v;
                    float e0, e1; elupair(v, e0, e1);
                    st[2 * r] = f2bf(e0); st[2 * r + 1] = f2bf(e1);
                }
                *(f32x4*)(resid + pb * 160 + ob) = rv;
                *(u16x8*)(ceout + pb * 320 + 2 * ob) = st;
            }
        }
    }
}

// ---------------------------------------------------------------------------
// nin_out: params = elu(ul) @ W^T + b, K=160, M padded to 128.
// ---------------------------------------------------------------------------
__global__ __launch_bounds__(256) void ninout_k(
    const float* __restrict__ ul, const unsigned short* __restrict__ wbn,
    const float* __restrict__ bias, float* __restrict__ params)
{
    constexpr int KCP = 40;
    __shared__ __align__(16) unsigned short bs[256 * KCP];
    __shared__ __align__(16) unsigned short wsm[32 * KCP];

    const int tid = threadIdx.x;
    const int wv = tid >> 6;
    const int lane = tid & 63;
    const int l16 = lane & 15;
    const int quad = lane >> 4;
    const int m0 = blockIdx.x * 32;
    const int bimg = blockIdx.y >> 2;
    const int rowbase = (blockIdx.y & 3) * 8;

    f32x4 acc[2][4];
#pragma unroll
    for (int mt = 0; mt < 2; ++mt)
#pragma unroll
        for (int ng = 0; ng < 4; ++ng)
#pragma unroll
            for (int r = 0; r < 4; ++r) acc[mt][ng][r] = 0.f;

    for (int k0 = 0; k0 < 160; k0 += 32) {
        __syncthreads();
        for (int e = tid; e < 256 * 8; e += 256) {
            int s = e & 7;
            int p = e >> 3;
            int pix = ((rowbase + (p >> 5)) << 5) | (p & 31);
            f32x4 xv = *(const f32x4*)(ul + (size_t)(((bimg << 10) | pix)) * 160 + k0 + s * 4);
            u16x4 st;
#pragma unroll
            for (int t = 0; t < 4; ++t) {
                float v = xv[t];
                st[t] = f2bf(v > 0.f ? v : expm1f(v));
            }
            *(u16x4*)(bs + p * KCP + s * 4) = st;
        }
        for (int e = tid; e < 32 * 4; e += 256) {
            int seg = e & 3;
            int mm = e >> 2;
            bf16x8 v = *(const bf16x8*)(wbn + (size_t)(m0 + mm) * 160 + k0 + seg * 8);
            *(bf16x8*)(wsm + mm * KCP + seg * 8) = v;
        }
        __syncthreads();
        bf16x8 af[2];
#pragma unroll
        for (int mt = 0; mt < 2; ++mt)
            af[mt] = *(const bf16x8*)&wsm[(mt * 16 + l16) * KCP + quad * 8];
#pragma unroll
        for (int ng = 0; ng < 4; ++ng) {
            int rl = 2 * wv + (ng >> 1);
            int cc = (ng & 1) * 16 + l16;
            bf16x8 bfr = *(const bf16x8*)&bs[(rl * 32 + cc) * KCP + quad * 8];
#pragma unroll
            for (int mt = 0; mt < 2; ++mt)
                acc[mt][ng] = __builtin_amdgcn_mfma_f32_16x16x32_bf16(af[mt], bfr, acc[mt][ng], 0, 0, 0);
        }
    }
#pragma unroll
    for (int mt = 0; mt < 2; ++mt)
#pragma unroll
        for (int ng = 0; ng < 4; ++ng) {
            int i = rowbase + 2 * wv + (ng >> 1);
            int j = (ng & 1) * 16 + l16;
            int pix = (i << 5) + j;
#pragma unroll
            for (int r = 0; r < 4; ++r) {
                int o = m0 + mt * 16 + quad * 4 + r;
                if (o < PCH)
                    params[(((size_t)bimg * PCH + o) << 10) + pix] = acc[mt][ng][r] + bias[o];
            }
        }
}

// ---------------------------------------------------------------------------
// DMLL — mix-parallel: 16 lanes per pixel, shfl_xor logsumexp.
// ---------------------------------------------------------------------------
__device__ __forceinline__ float softplus_f(float v) {
    return fmaxf(v, 0.f) + log1pf(expf(-fabsf(v)));
}
__device__ __forceinline__ float sigmoid_f(float v) { return 1.f / (1.f + expf(-v)); }
__device__ __forceinline__ float lpterm(float x, float m, float ls) {
    float inv = expf(-ls);
    float cen = x - m;
    float plus = inv * (cen + 0.00392156862745098f);
    float minv = inv * (cen - 0.00392156862745098f);
    float cdf_delta = sigmoid_f(plus) - sigmoid_f(minv);
    float log_cdf_plus = plus - softplus_f(plus);
    float log_om = -softplus_f(minv);
    float mid = inv * cen;
    float log_pdf_mid = mid - ls - 2.f * softplus_f(mid);
    float inner = (cdf_delta > 1e-5f) ? logf(fmaxf(cdf_delta, 1e-12f))
                                      : (log_pdf_mid - 4.848116389675623f);
    return (x < -0.999f) ? log_cdf_plus : ((x > 0.999f) ? log_om : inner);
}

__global__ __launch_bounds__(256) void dmll_k(
    const float* __restrict__ smp, const float* __restrict__ params,
    float* __restrict__ partials)
{
    const int tid = threadIdx.x;
    const int n = tid & 15;
    const int ploc = tid >> 4;
    const int pix_g = blockIdx.x * 16 + ploc;
    const int b = pix_g >> 10;
    const int ij = pix_g & 1023;
    const float* P = params + ((size_t)b * PCH << 10) + ij;

    float x0 = smp[(((size_t)b * 3 + 0) << 10) + ij] * 2.f - 1.f;
    float x1 = smp[(((size_t)b * 3 + 1) << 10) + ij] * 2.f - 1.f;
    float x2 = smp[(((size_t)b * 3 + 2) << 10) + ij] * 2.f - 1.f;

    float logit = -1e30f;
    if (n < NMIX) logit = P[(size_t)n << 10];
    float mx = logit;
#pragma unroll
    for (int m = 1; m < 16; m <<= 1) mx = fmaxf(mx, __shfl_xor(mx, m, 16));
    float ex = (n < NMIX) ? expf(logit - mx) : 0.f;
    float se = ex;
#pragma unroll
    for (int m = 1; m < 16; m <<= 1) se += __shfl_xor(se, m, 16);
    float lse_logit = mx + logf(se);

    float lp = -1e30f;
    if (n < NMIX) {
        float mean0 = P[(size_t)(10 + n) << 10];
        float mean1 = P[(size_t)(40 + n) << 10];
        float mean2 = P[(size_t)(70 + n) << 10];
        float ls0 = fmaxf(P[(size_t)(20 + n) << 10], -7.f);
        float ls1 = fmaxf(P[(size_t)(50 + n) << 10], -7.f);
        float ls2 = fmaxf(P[(size_t)(80 + n) << 10], -7.f);
        float c0 = tanhf(P[(size_t)(30 + n) << 10]);
        float c1 = tanhf(P[(size_t)(60 + n) << 10]);
        float c2 = tanhf(P[(size_t)(90 + n) << 10]);
        float m0 = mean0;
        float m1 = mean1 + c0 * x0;
        float m2 = mean2 + c1 * x0 + c2 * x1;
        float s3 = lpterm(x0, m0, ls0) + lpterm(x1, m1, ls1) + lpterm(x2, m2, ls2);
        lp = s3 + logit - lse_logit;
    }
    float mx2 = lp;
#pragma unroll
    for (int m = 1; m < 16; m <<= 1) mx2 = fmaxf(mx2, __shfl_xor(mx2, m, 16));
    float e2 = (n < NMIX) ? expf(lp - mx2) : 0.f;
    float se2 = e2;
#pragma unroll
    for (int m = 1; m < 16; m <<= 1) se2 += __shfl_xor(se2, m, 16);
    float v = (n == 0) ? (mx2 + logf(se2)) : 0.f;

#pragma unroll
    for (int off = 32; off > 0; off >>= 1) v += __shfl_down(v, off);
    __shared__ float red[4];
    if ((tid & 63) == 0) red[tid >> 6] = v;
    __syncthreads();
    if (tid == 0) partials[blockIdx.x] = red[0] + red[1] + red[2] + red[3];
}

__global__ __launch_bounds__(256) void dmll_final_k(
    const float* __restrict__ partials, float* __restrict__ out)
{
    float v = 0.f;
    for (int k = threadIdx.x; k < 2048; k += 256) v += partials[k];
#pragma unroll
    for (int off = 32; off > 0; off >>= 1) v += __shfl_down(v, off);
    __shared__ float red[4];
    if ((threadIdx.x & 63) == 0) red[threadIdx.x >> 6] = v;
    __syncthreads();
    if (threadIdx.x == 0) out[0] = red[0] + red[1] + red[2] + red[3];
}

// ---------------------------------------------------------------------------
extern "C" void kernel_launch(void* const* d_in, const int* in_sizes, int n_in,
                              void* d_out, int out_size, void* d_ws, size_t ws_size,
                              hipStream_t stream)
{
    const float* samples   = (const float*)d_in[0];
    const float* w_u_init  = (const float*)d_in[1];
    const float* b_u_init  = (const float*)d_in[2];
    const float* w_ul_d    = (const float*)d_in[3];
    const float* b_ul_d    = (const float*)d_in[4];
    const float* w_ul_dr   = (const float*)d_in[5];
    const float* b_ul_dr   = (const float*)d_in[6];
    const float* u_c1_w    = (const float*)d_in[7];
    const float* u_c1_b    = (const float*)d_in[8];
    const float* u_c2_w    = (const float*)d_in[9];
    const float* u_c2_b    = (const float*)d_in[10];
    const float* ul_c1_w   = (const float*)d_in[11];
    const float* ul_c1_b   = (const float*)d_in[12];
    const float* ul_nin_w  = (const float*)d_in[13];
    const float* ul_nin_b  = (const float*)d_in[14];
    const float* ul_c2_w   = (const float*)d_in[15];
    const float* ul_c2_b   = (const float*)d_in[16];
    const float* nin_out_w = (const float*)d_in[17];
    const float* nin_out_b = (const float*)d_in[18];
    float* out = (float*)d_out;

    const size_t NU = (size_t)BZ * FCH * 1024;  // 5,242,880
    float* u  = (float*)d_ws;                    // [b][pix][160]
    float* ul = u + NU;
    unsigned short* CEu  = (unsigned short*)(ul + NU);   // [b][pix][320]
    unsigned short* CEc1 = CEu + 2 * NU;
    unsigned short* CEul = CEc1 + 2 * NU;
    unsigned short* WBu1  = CEul + 2 * NU;
    unsigned short* WBu2  = WBu1 + (size_t)5 * 160 * 6 * 320;
    unsigned short* WBul1 = WBu2 + (size_t)5 * 320 * 6 * 320;
    unsigned short* WBnin = WBul1 + (size_t)5 * 160 * 4 * 320;
    unsigned short* WBul2 = WBnin + (size_t)5 * 160 * 1 * 320;
    unsigned short* WBnout = WBul2 + (size_t)5 * 320 * 4 * 320;
    float* partials = (float*)(WBnout + (size_t)128 * 160);   // 2048 floats
    float* zguard = partials + 2048;                          // 2KB zeros
    float* params = (float*)CEc1;  // CEc1 dead once ninout runs

    dim3 blk(256);

    // coalesced LDS-transpose repacks: grid = (CoutPad, NB)
    repack_k<<<dim3(160, 5), blk, 0, stream>>>(u_c1_w,    WBu1,  160, 320, 6, 1);
    repack_k<<<dim3(320, 5), blk, 0, stream>>>(u_c2_w,    WBu2,  320, 320, 6, 1);
    repack_k<<<dim3(160, 5), blk, 0, stream>>>(ul_c1_w,   WBul1, 160, 320, 4, 1);
    repack_k<<<dim3(160, 5), blk, 0, stream>>>(ul_nin_w,  WBnin, 160, 320, 1, 1);
    repack_k<<<dim3(320, 5), blk, 0, stream>>>(ul_c2_w,   WBul2, 320, 320, 4, 1);
    repack_k<<<dim3(128, 1), blk, 0, stream>>>(nin_out_w, WBnout, 100, 160, 1, 0);

    init_both_k<<<dim3(32, 32), blk, 0, stream>>>(
        samples, w_u_init, b_u_init, w_ul_d, b_ul_d, w_ul_dr, b_ul_dr,
        u, ul, CEu, CEul, zguard);

    const unsigned short* zg = (const unsigned short*)zguard;
    for (int t = 0; t < 5; ++t) {
        conv_mfma_k<2, 3, 1, 1, false, false, 32, true><<<640, blk, 0, stream>>>(
            CEu, WBu1 + (size_t)t * 160 * 6 * 320, nullptr, nullptr,
            u_c1_b + t * 160, nullptr, nullptr, CEc1, zg);
        conv_mfma_k<2, 3, 1, 1, false, true, 64, false><<<640, blk, 0, stream>>>(
            CEc1, WBu2 + (size_t)t * 320 * 6 * 320, nullptr, nullptr,
            u_c2_b + t * 320, nullptr, u, CEu, zg);
        conv_mfma_k<2, 2, 1, 1, true, false, 32, true><<<640, blk, 0, stream>>>(
            CEul, WBul1 + (size_t)t * 160 * 4 * 320, CEu, WBnin + (size_t)t * 160 * 320,
            ul_c1_b + t * 160, ul_nin_b + t * 160, nullptr, CEc1, zg);
        conv_mfma_k<2, 2, 1, 1, false, true, 64, true><<<640, blk, 0, stream>>>(
            CEc1, WBul2 + (size_t)t * 320 * 4 * 320, nullptr, nullptr,
            ul_c2_b + t * 320, nullptr, ul, CEul, zg);
    }

    ninout_k<<<dim3(4, 128), blk, 0, stream>>>(ul, WBnout, nin_out_b, params);
    dmll_k<<<2048, blk, 0, stream>>>(samples, params, partials);
    dmll_final_k<<<1, 256, 0, stream>>>(partials, out);
}

// Round 10
// 969.450 us; speedup vs baseline: 1.3030x; 1.3030x over previous
//
#include <hip/hip_runtime.h>
#include <math.h>

#define BZ 32
#define FCH 160
#define NMIX 10
#define PCH 100

typedef __attribute__((ext_vector_type(8))) short bf16x8;
typedef __attribute__((ext_vector_type(8))) unsigned short u16x8;
typedef __attribute__((ext_vector_type(4))) unsigned short u16x4;
typedef __attribute__((ext_vector_type(4))) float f32x4;

__device__ __forceinline__ unsigned short f2bf(float f) {
    union { float f; unsigned u; } x; x.f = f;
    return (unsigned short)((x.u + 0x7FFFu + ((x.u >> 16) & 1u)) >> 16);
}
__device__ __forceinline__ void elupair(float v, float& e0, float& e1) {
    if (v > 0.f) { e0 = v; e1 = expm1f(-v); }
    else         { e0 = expm1f(v); e1 = -v; }
}
// LDS swizzle (read side): row p of 32 halfwords, 4 segs of 8hw (16B).
// slot = seg ^ f(p). Staging writes are linear (global_load_lds: lane*16B);
// the swizzle is applied on the SOURCE address (seg_src = (lane&3) ^ f(row)).
__device__ __forceinline__ int fsw(int p) { return (p + (p >> 2)) & 3; }
__device__ __forceinline__ int swz(int p, int seg) {
    return p * 32 + ((seg ^ fsw(p)) << 3);
}
__device__ __forceinline__ void load_lds16(const unsigned short* g, unsigned short* l) {
    __builtin_amdgcn_global_load_lds(
        (const __attribute__((address_space(1))) unsigned int*)g,
        (__attribute__((address_space(3))) unsigned int*)l, 16, 0, 0);
}

// ---------------------------------------------------------------------------
// Weight repack: w[NB][Cout][Cin][NT] fp32 -> wb[NB][CoutPad][NT][Cin] bf16,
// optional concat-elu K interleave. Block per (nb,o): coalesced LDS transpose.
// ---------------------------------------------------------------------------
__global__ __launch_bounds__(256) void repack_k(
    const float* __restrict__ w, unsigned short* __restrict__ wb,
    int Cout, int Cin, int NT, int ILV)
{
    __shared__ float ws[1920];
    const int o = blockIdx.x;            // < CoutPad
    const int nb = blockIdx.y;
    const int CoutPad = gridDim.x;
    const int n = Cin * NT;
    unsigned short* dst = wb + (size_t)(nb * CoutPad + o) * n;
    if (o >= Cout) {
        for (int e = threadIdx.x; e < n; e += 256) dst[e] = 0;
        return;
    }
    const float* src = w + (size_t)(nb * Cout + o) * n;
    for (int e = threadIdx.x; e < n; e += 256) ws[e] = src[e];
    __syncthreads();
    const int half = Cin >> 1;
    for (int e = threadIdx.x; e < n; e += 256) {
        int tap = e / Cin;
        int k = e - tap * Cin;
        int csrc = ILV ? ((k & 1) ? (half + (k >> 1)) : (k >> 1)) : k;
        dst[e] = f2bf(ws[csrc * NT + tap]);
    }
}

// ---------------------------------------------------------------------------
// Fused init convs: one block per (row i, batch b). Block (0,0) also zeroes
// the conv guard buffer.
// ---------------------------------------------------------------------------
__global__ __launch_bounds__(256) void init_both_k(
    const float* __restrict__ smp,
    const float* __restrict__ wu_g, const float* __restrict__ bu_g,
    const float* __restrict__ wd_g, const float* __restrict__ bd_g,
    const float* __restrict__ wr_g, const float* __restrict__ br_g,
    float* __restrict__ u, float* __restrict__ ul,
    unsigned short* __restrict__ ceu, unsigned short* __restrict__ ceul,
    float* __restrict__ zg)
{
    __shared__ float wU[160 * 24];
    __shared__ float wD[160 * 12];
    __shared__ float wR[160 * 8];
    __shared__ float bU[160], bD[160], bR[160];
    __shared__ float X[3][4][34];

    const int tid = threadIdx.x;
    const int i = blockIdx.x;
    const int b = blockIdx.y;

    if (i == 0 && b == 0 && tid < 128) {
        f32x4 z = {0.f, 0.f, 0.f, 0.f};
        ((f32x4*)zg)[tid] = z;
    }

    for (int e = tid; e < 160 * 24; e += 256) wU[e] = wu_g[e];
    for (int e = tid; e < 160 * 12; e += 256) wD[e] = wd_g[e];
    for (int e = tid; e < 160 * 8;  e += 256) wR[e] = wr_g[e];
    if (tid < 160) { bU[tid] = bu_g[tid]; bD[tid] = bd_g[tid]; bR[tid] = br_g[tid]; }
    for (int e = tid; e < 3 * 4 * 34; e += 256) {
        int col = e % 34;
        int c = (e / 34) & 3;
        int rs = e / (34 * 4);
        int r = i - 2 + rs;
        int jj = col - 1;
        float v = 0.f;
        if ((unsigned)r < 32u && (unsigned)jj < 32u)
            v = (c < 3) ? (smp[(((size_t)b * 3 + c) << 10) + (r << 5) + jj] * 2.f - 1.f)
                        : 1.f;
        X[rs][c][col] = v;
    }
    __syncthreads();
    if (tid >= 160) return;
    const int o = tid;

    float wu_r[24], wd_r[12], wr_r[8];
#pragma unroll
    for (int q = 0; q < 24; ++q) wu_r[q] = wU[o * 24 + q];
#pragma unroll
    for (int q = 0; q < 12; ++q) wd_r[q] = wD[o * 12 + q];
#pragma unroll
    for (int q = 0; q < 8; ++q)  wr_r[q] = wR[o * 8 + q];
    const float bu_v = (i > 0) ? bU[o] : 0.f;
    const float bd_v = (i >= 1) ? bD[o] : 0.f;
    const float br_v = bR[o];

    for (int j = 0; j < 32; ++j) {
        float su = 0.f, sd = 0.f, sr = 0.f;
#pragma unroll
        for (int c = 0; c < 4; ++c) {
            float x00 = X[0][c][j], x01 = X[0][c][j + 1], x02 = X[0][c][j + 2];
            float x10 = X[1][c][j], x11 = X[1][c][j + 1], x12 = X[1][c][j + 2];
            float x20 = X[2][c][j];
            su += wu_r[c * 6 + 0] * x00 + wu_r[c * 6 + 1] * x01 + wu_r[c * 6 + 2] * x02
                + wu_r[c * 6 + 3] * x10 + wu_r[c * 6 + 4] * x11 + wu_r[c * 6 + 5] * x12;
            sd += wd_r[c * 3 + 0] * x10 + wd_r[c * 3 + 1] * x11 + wd_r[c * 3 + 2] * x12;
            sr += wr_r[c * 2 + 0] * x10 + wr_r[c * 2 + 1] * x20;
        }
        float uv = (i > 0) ? (su + bu_v) : 0.f;
        float ulv = sd + bd_v + sr + ((j >= 1) ? br_v : 0.f);

        size_t base = (size_t)((b << 10) | (i << 5) | j);
        u[base * 160 + o] = uv;
        ul[base * 160 + o] = ulv;
        float e0, e1;
        elupair(uv, e0, e1);
        unsigned pu = (unsigned)f2bf(e0) | ((unsigned)f2bf(e1) << 16);
        *(unsigned*)(ceu + base * 320 + 2 * o) = pu;
        elupair(ulv, e0, e1);
        unsigned pl = (unsigned)f2bf(e0) | ((unsigned)f2bf(e1) << 16);
        *(unsigned*)(ceul + base * 320 + 2 * o) = pl;
    }
}

// ---------------------------------------------------------------------------
// MFMA implicit-GEMM conv body (round-8 single-buffer schedule, best
// measured: TLP > intra-block pipelining, confirmed r3/r7/r9).
// LDS comes from the caller's dynamic allocation so fused kernels share one
// block (max of jobs, not sum). XCD-aware decode on the LOCAL bid.
// ---------------------------------------------------------------------------
template<int KH, int KW, int PT, int PL, bool DUAL, bool GATE, int MBLK>
__device__ __forceinline__ void conv_body(
    int bid, unsigned short* smem,
    const unsigned short* __restrict__ cein,
    const unsigned short* __restrict__ wb,
    const unsigned short* __restrict__ cein2,
    const unsigned short* __restrict__ wb2,
    const float* __restrict__ bias, const float* __restrict__ bias2,
    float* __restrict__ resid,
    unsigned short* __restrict__ ceout,
    const unsigned short* __restrict__ zguard)
{
    constexpr int NT = KH * KW;
    constexpr int RW = 8 + KH - 1;                  // 9
    constexpr int CW = 32 + KW - 1;                 // 33/34
    constexpr int MTILES = MBLK / 16;
    constexpr int MSH = (MBLK == 32) ? 5 : 6;
    constexpr int NSA = NT * MBLK / 64;
    constexpr int NSB = (RW * CW * 4 + 255) / 256;  // 5
    constexpr int BSZ = NSB * 64 * 32;              // halfwords

    unsigned short* bs = smem;
    unsigned short* wsm = smem + BSZ;

    const int tid = threadIdx.x;
    const int wv = tid >> 6;
    const int lane = tid & 63;
    const int l16 = lane & 15;
    const int quad = lane >> 4;

    // XCD-aware decode (local grid = 640 = 8 XCDs * 16 ytiles * 5 mtiles)
    const int q8 = bid >> 3;
    const int yt = (bid & 7) * 16 + q8 / 5;         // pixel tile 0..127
    const int m0 = (q8 % 5) * 32;
    const int bimg = yt >> 2;
    const int rowbase = (yt & 3) * 8;

    const int sd = lane & 3;        // dest seg slot (linear DMA)
    const int lr = lane >> 2;       // row-within-16

    // ---- per-lane staging sources, computed ONCE (ci*32 added per chunk)
    const unsigned short* srcA[NSA];
#pragma unroll
    for (int it = 0; it < NSA; ++it) {
        int row = it * 64 + wv * 16 + lr;           // = tap*MBLK + mm
        int tap = row >> MSH;
        int mm = row & (MBLK - 1);
        int o = GATE ? (mm < 32 ? m0 + mm : 128 + m0 + mm) : (m0 + mm);
        int ss = sd ^ fsw(row);
        srcA[it] = wb + ((size_t)o * NT + tap) * 320 + ss * 8;
    }
    const unsigned short* srcB[NSB];
#pragma unroll
    for (int it = 0; it < NSB; ++it) {
        int p = it * 64 + wv * 16 + lr;
        int r = p / CW;
        int c = p - r * CW;
        int grow = rowbase + r - PT;
        int gcol = c - PL;
        int ss = sd ^ fsw(p);
        bool ok = (p < RW * CW) && ((unsigned)grow < 32u) && ((unsigned)gcol < 32u);
        srcB[it] = ok ? cein + (size_t)(((bimg << 10) | (grow << 5) | gcol)) * 320 + ss * 8
                      : zguard;
    }

    f32x4 acc[MTILES][4];
#pragma unroll
    for (int mt = 0; mt < MTILES; ++mt)
#pragma unroll
        for (int ng = 0; ng < 4; ++ng)
#pragma unroll
            for (int r = 0; r < 4; ++r) acc[mt][ng][r] = 0.f;

    for (int k0 = 0; k0 < 320; k0 += 32) {
        __syncthreads();                 // previous compute done reading LDS
#pragma unroll
        for (int it = 0; it < NSB; ++it)
            load_lds16(srcB[it] + k0, &bs[(it * 64 + wv * 16) * 32]);
#pragma unroll
        for (int it = 0; it < NSA; ++it)
            load_lds16(srcA[it] + k0, &wsm[(it * 64 + wv * 16) * 32]);
        __syncthreads();                 // drains vmcnt -> LDS ready
#pragma unroll
        for (int tap = 0; tap < NT; ++tap) {
            const int kh = tap / KW, kw = tap % KW;
            bf16x8 af[MTILES];
#pragma unroll
            for (int mt = 0; mt < MTILES; ++mt)
                af[mt] = *(const bf16x8*)&wsm[swz(tap * MBLK + mt * 16 + l16, quad)];
#pragma unroll
            for (int ng = 0; ng < 4; ++ng) {
                int rl = 2 * wv + (ng >> 1) + kh;
                int cc = (ng & 1) * 16 + l16 + kw;
                bf16x8 bfr = *(const bf16x8*)&bs[swz(rl * CW + cc, quad)];
#pragma unroll
                for (int mt = 0; mt < MTILES; ++mt)
                    acc[mt][ng] = __builtin_amdgcn_mfma_f32_16x16x32_bf16(af[mt], bfr, acc[mt][ng], 0, 0, 0);
            }
        }
    }

    if (DUAL) {  // fused 1x1 nin over second CE input (MBLK==32 path)
        const unsigned short* srcB2[4];
#pragma unroll
        for (int it = 0; it < 4; ++it) {
            int p2 = it * 64 + wv * 16 + lr;
            int r = p2 >> 5, c = p2 & 31;
            int ss = sd ^ fsw(p2);
            srcB2[it] = cein2 + (size_t)(((bimg << 10) | ((rowbase + r) << 5) | c)) * 320 + ss * 8;
        }
        int row2 = wv * 16 + lr;                    // valid for wv<2
        int mm2 = row2 & 31;
        const unsigned short* srcA2 =
            wb2 + (size_t)(m0 + mm2) * 320 + (sd ^ fsw(row2)) * 8;

        for (int k0 = 0; k0 < 320; k0 += 32) {
            __syncthreads();
#pragma unroll
            for (int it = 0; it < 4; ++it)
                load_lds16(srcB2[it] + k0, &bs[(it * 64 + wv * 16) * 32]);
            if (wv < 2)
                load_lds16(srcA2 + k0, &wsm[(wv * 16) * 32]);
            __syncthreads();
            bf16x8 af[MTILES];
#pragma unroll
            for (int mt = 0; mt < MTILES; ++mt)
                af[mt] = *(const bf16x8*)&wsm[swz(mt * 16 + l16, quad)];
#pragma unroll
            for (int ng = 0; ng < 4; ++ng) {
                int rl = 2 * wv + (ng >> 1);
                int cc = (ng & 1) * 16 + l16;
                bf16x8 bfr = *(const bf16x8*)&bs[swz(rl * 32 + cc, quad)];
#pragma unroll
                for (int mt = 0; mt < MTILES; ++mt)
                    acc[mt][ng] = __builtin_amdgcn_mfma_f32_16x16x32_bf16(af[mt], bfr, acc[mt][ng], 0, 0, 0);
            }
        }
    }

    // ---- epilogue (vectorized channel-last stores)
    constexpr int MOUT = GATE ? MTILES / 2 : MTILES;
#pragma unroll
    for (int mt = 0; mt < MOUT; ++mt) {
        int ob = m0 + mt * 16 + quad * 4;
        f32x4 bv = *(const f32x4*)(bias + ob);
        f32x4 bv2;
        if (DUAL) bv2 = *(const f32x4*)(bias2 + ob);
        f32x4 bg;
        if (GATE) bg = *(const f32x4*)(bias + ob + 160);
#pragma unroll
        for (int ng = 0; ng < 4; ++ng) {
            int i = rowbase + 2 * wv + (ng >> 1);
            int j = (ng & 1) * 16 + l16;
            size_t pb = (size_t)((bimg << 10) | (i << 5) | j);
            if (!GATE) {
                u16x8 st;
#pragma unroll
                for (int r = 0; r < 4; ++r) {
                    float v = acc[mt][ng][r] + bv[r] + (DUAL ? bv2[r] : 0.f);
                    float e0, e1; elupair(v, e0, e1);
                    st[2 * r] = f2bf(e0); st[2 * r + 1] = f2bf(e1);
                }
                *(u16x8*)(ceout + pb * 320 + 2 * ob) = st;
            } else {
                f32x4 rv = *(const f32x4*)(resid + pb * 160 + ob);
                u16x8 st;
#pragma unroll
                for (int r = 0; r < 4; ++r) {
                    float g1 = acc[mt][ng][r] + bv[r];
                    float g2 = acc[mt + MTILES / 2][ng][r] + bg[r];
                    float v = rv[r] + g1 / (1.f + expf(-g2));
                    rv[r] = v;
                    float e0, e1; elupair(v, e0, e1);
                    st[2 * r] = f2bf(e0); st[2 * r + 1] = f2bf(e1);
                }
                *(f32x4*)(resid + pb * 160 + ob) = rv;
                *(u16x8*)(ceout + pb * 320 + 2 * ob) = st;
            }
        }
    }
}

template<int KH, int KW, int PT, int PL, bool DUAL, bool GATE, int MBLK>
__global__ __launch_bounds__(256) void conv_single_k(
    const unsigned short* __restrict__ cein, const unsigned short* __restrict__ wb,
    const unsigned short* __restrict__ cein2, const unsigned short* __restrict__ wb2,
    const float* __restrict__ bias, const float* __restrict__ bias2,
    float* __restrict__ resid, unsigned short* __restrict__ ceout,
    const unsigned short* __restrict__ zguard)
{
    extern __shared__ __align__(16) unsigned short dsm[];
    conv_body<KH, KW, PT, PL, DUAL, GATE, MBLK>(
        blockIdx.x, dsm, cein, wb, cein2, wb2, bias, bias2, resid, ceout, zguard);
}

// fused: blocks 0-639 = ul_c1(t) [2x2 DUAL M32]; 640-1279 = u_c1(t+1) [2x3 M32]
__global__ __launch_bounds__(256) void conv_fused_c1_k(
    const unsigned short* __restrict__ ceul, const unsigned short* __restrict__ wul1,
    const unsigned short* __restrict__ ceu_nin, const unsigned short* __restrict__ wnin,
    const float* __restrict__ bul1, const float* __restrict__ bnin,
    unsigned short* __restrict__ cec1ul,
    const unsigned short* __restrict__ ceu, const unsigned short* __restrict__ wu1,
    const float* __restrict__ bu1, unsigned short* __restrict__ cec1u,
    const unsigned short* __restrict__ zguard)
{
    extern __shared__ __align__(16) unsigned short dsm[];
    if (blockIdx.x < 640)
        conv_body<2, 2, 1, 1, true, false, 32>(
            blockIdx.x, dsm, ceul, wul1, ceu_nin, wnin, bul1, bnin, nullptr, cec1ul, zguard);
    else
        conv_body<2, 3, 1, 1, false, false, 32>(
            blockIdx.x - 640, dsm, ceu, wu1, nullptr, nullptr, bu1, nullptr, nullptr, cec1u, zguard);
}

// fused: blocks 0-639 = ul_c2(t) [2x2 GATE M64]; 640-1279 = u_c2(t+1) [2x3 GATE M64]
__global__ __launch_bounds__(256) void conv_fused_c2_k(
    const unsigned short* __restrict__ cec1ul, const unsigned short* __restrict__ wul2,
    const float* __restrict__ bul2, float* __restrict__ ul_r,
    unsigned short* __restrict__ ceul,
    const unsigned short* __restrict__ cec1u, const unsigned short* __restrict__ wu2,
    const float* __restrict__ bu2, float* __restrict__ u_r,
    unsigned short* __restrict__ ceu,
    const unsigned short* __restrict__ zguard)
{
    extern __shared__ __align__(16) unsigned short dsm[];
    if (blockIdx.x < 640)
        conv_body<2, 2, 1, 1, false, true, 64>(
            blockIdx.x, dsm, cec1ul, wul2, nullptr, nullptr, bul2, nullptr, ul_r, ceul, zguard);
    else
        conv_body<2, 3, 1, 1, false, true, 64>(
            blockIdx.x - 640, dsm, cec1u, wu2, nullptr, nullptr, bu2, nullptr, u_r, ceu, zguard);
}

// ---------------------------------------------------------------------------
// nin_out: params = elu(ul) @ W^T + b, K=160, M padded to 128.
// ---------------------------------------------------------------------------
__global__ __launch_bounds__(256) void ninout_k(
    const float* __restrict__ ul, const unsigned short* __restrict__ wbn,
    const float* __restrict__ bias, float* __restrict__ params)
{
    constexpr int KCP = 40;
    __shared__ __align__(16) unsigned short bs[256 * KCP];
    __shared__ __align__(16) unsigned short wsm[32 * KCP];

    const int tid = threadIdx.x;
    const int wv = tid >> 6;
    const int lane = tid & 63;
    const int l16 = lane & 15;
    const int quad = lane >> 4;
    const int m0 = blockIdx.x * 32;
    const int bimg = blockIdx.y >> 2;
    const int rowbase = (blockIdx.y & 3) * 8;

    f32x4 acc[2][4];
#pragma unroll
    for (int mt = 0; mt < 2; ++mt)
#pragma unroll
        for (int ng = 0; ng < 4; ++ng)
#pragma unroll
            for (int r = 0; r < 4; ++r) acc[mt][ng][r] = 0.f;

    for (int k0 = 0; k0 < 160; k0 += 32) {
        __syncthreads();
        for (int e = tid; e < 256 * 8; e += 256) {
            int s = e & 7;
            int p = e >> 3;
            int pix = ((rowbase + (p >> 5)) << 5) | (p & 31);
            f32x4 xv = *(const f32x4*)(ul + (size_t)(((bimg << 10) | pix)) * 160 + k0 + s * 4);
            u16x4 st;
#pragma unroll
            for (int t = 0; t < 4; ++t) {
                float v = xv[t];
                st[t] = f2bf(v > 0.f ? v : expm1f(v));
            }
            *(u16x4*)(bs + p * KCP + s * 4) = st;
        }
        for (int e = tid; e < 32 * 4; e += 256) {
            int seg = e & 3;
            int mm = e >> 2;
            bf16x8 v = *(const bf16x8*)(wbn + (size_t)(m0 + mm) * 160 + k0 + seg * 8);
            *(bf16x8*)(wsm + mm * KCP + seg * 8) = v;
        }
        __syncthreads();
        bf16x8 af[2];
#pragma unroll
        for (int mt = 0; mt < 2; ++mt)
            af[mt] = *(const bf16x8*)&wsm[(mt * 16 + l16) * KCP + quad * 8];
#pragma unroll
        for (int ng = 0; ng < 4; ++ng) {
            int rl = 2 * wv + (ng >> 1);
            int cc = (ng & 1) * 16 + l16;
            bf16x8 bfr = *(const bf16x8*)&bs[(rl * 32 + cc) * KCP + quad * 8];
#pragma unroll
            for (int mt = 0; mt < 2; ++mt)
                acc[mt][ng] = __builtin_amdgcn_mfma_f32_16x16x32_bf16(af[mt], bfr, acc[mt][ng], 0, 0, 0);
        }
    }
#pragma unroll
    for (int mt = 0; mt < 2; ++mt)
#pragma unroll
        for (int ng = 0; ng < 4; ++ng) {
            int i = rowbase + 2 * wv + (ng >> 1);
            int j = (ng & 1) * 16 + l16;
            int pix = (i << 5) + j;
#pragma unroll
            for (int r = 0; r < 4; ++r) {
                int o = m0 + mt * 16 + quad * 4 + r;
                if (o < PCH)
                    params[(((size_t)bimg * PCH + o) << 10) + pix] = acc[mt][ng][r] + bias[o];
            }
        }
}

// ---------------------------------------------------------------------------
// DMLL — mix-parallel: 16 lanes per pixel, shfl_xor logsumexp.
// ---------------------------------------------------------------------------
__device__ __forceinline__ float softplus_f(float v) {
    return fmaxf(v, 0.f) + log1pf(expf(-fabsf(v)));
}
__device__ __forceinline__ float sigmoid_f(float v) { return 1.f / (1.f + expf(-v)); }
__device__ __forceinline__ float lpterm(float x, float m, float ls) {
    float inv = expf(-ls);
    float cen = x - m;
    float plus = inv * (cen + 0.00392156862745098f);
    float minv = inv * (cen - 0.00392156862745098f);
    float cdf_delta = sigmoid_f(plus) - sigmoid_f(minv);
    float log_cdf_plus = plus - softplus_f(plus);
    float log_om = -softplus_f(minv);
    float mid = inv * cen;
    float log_pdf_mid = mid - ls - 2.f * softplus_f(mid);
    float inner = (cdf_delta > 1e-5f) ? logf(fmaxf(cdf_delta, 1e-12f))
                                      : (log_pdf_mid - 4.848116389675623f);
    return (x < -0.999f) ? log_cdf_plus : ((x > 0.999f) ? log_om : inner);
}

__global__ __launch_bounds__(256) void dmll_k(
    const float* __restrict__ smp, const float* __restrict__ params,
    float* __restrict__ partials)
{
    const int tid = threadIdx.x;
    const int n = tid & 15;
    const int ploc = tid >> 4;
    const int pix_g = blockIdx.x * 16 + ploc;
    const int b = pix_g >> 10;
    const int ij = pix_g & 1023;
    const float* P = params + ((size_t)b * PCH << 10) + ij;

    float x0 = smp[(((size_t)b * 3 + 0) << 10) + ij] * 2.f - 1.f;
    float x1 = smp[(((size_t)b * 3 + 1) << 10) + ij] * 2.f - 1.f;
    float x2 = smp[(((size_t)b * 3 + 2) << 10) + ij] * 2.f - 1.f;

    float logit = -1e30f;
    if (n < NMIX) logit = P[(size_t)n << 10];
    float mx = logit;
#pragma unroll
    for (int m = 1; m < 16; m <<= 1) mx = fmaxf(mx, __shfl_xor(mx, m, 16));
    float ex = (n < NMIX) ? expf(logit - mx) : 0.f;
    float se = ex;
#pragma unroll
    for (int m = 1; m < 16; m <<= 1) se += __shfl_xor(se, m, 16);
    float lse_logit = mx + logf(se);

    float lp = -1e30f;
    if (n < NMIX) {
        float mean0 = P[(size_t)(10 + n) << 10];
        float mean1 = P[(size_t)(40 + n) << 10];
        float mean2 = P[(size_t)(70 + n) << 10];
        float ls0 = fmaxf(P[(size_t)(20 + n) << 10], -7.f);
        float ls1 = fmaxf(P[(size_t)(50 + n) << 10], -7.f);
        float ls2 = fmaxf(P[(size_t)(80 + n) << 10], -7.f);
        float c0 = tanhf(P[(size_t)(30 + n) << 10]);
        float c1 = tanhf(P[(size_t)(60 + n) << 10]);
        float c2 = tanhf(P[(size_t)(90 + n) << 10]);
        float m0 = mean0;
        float m1 = mean1 + c0 * x0;
        float m2 = mean2 + c1 * x0 + c2 * x1;
        float s3 = lpterm(x0, m0, ls0) + lpterm(x1, m1, ls1) + lpterm(x2, m2, ls2);
        lp = s3 + logit - lse_logit;
    }
    float mx2 = lp;
#pragma unroll
    for (int m = 1; m < 16; m <<= 1) mx2 = fmaxf(mx2, __shfl_xor(mx2, m, 16));
    float e2 = (n < NMIX) ? expf(lp - mx2) : 0.f;
    float se2 = e2;
#pragma unroll
    for (int m = 1; m < 16; m <<= 1) se2 += __shfl_xor(se2, m, 16);
    float v = (n == 0) ? (mx2 + logf(se2)) : 0.f;

#pragma unroll
    for (int off = 32; off > 0; off >>= 1) v += __shfl_down(v, off);
    __shared__ float red[4];
    if ((tid & 63) == 0) red[tid >> 6] = v;
    __syncthreads();
    if (tid == 0) partials[blockIdx.x] = red[0] + red[1] + red[2] + red[3];
}

__global__ __launch_bounds__(256) void dmll_final_k(
    const float* __restrict__ partials, float* __restrict__ out)
{
    float v = 0.f;
    for (int k = threadIdx.x; k < 2048; k += 256) v += partials[k];
#pragma unroll
    for (int off = 32; off > 0; off >>= 1) v += __shfl_down(v, off);
    __shared__ float red[4];
    if ((threadIdx.x & 63) == 0) red[threadIdx.x >> 6] = v;
    __syncthreads();
    if (threadIdx.x == 0) out[0] = red[0] + red[1] + red[2] + red[3];
}

// ---------------------------------------------------------------------------
extern "C" void kernel_launch(void* const* d_in, const int* in_sizes, int n_in,
                              void* d_out, int out_size, void* d_ws, size_t ws_size,
                              hipStream_t stream)
{
    const float* samples   = (const float*)d_in[0];
    const float* w_u_init  = (const float*)d_in[1];
    const float* b_u_init  = (const float*)d_in[2];
    const float* w_ul_d    = (const float*)d_in[3];
    const float* b_ul_d    = (const float*)d_in[4];
    const float* w_ul_dr   = (const float*)d_in[5];
    const float* b_ul_dr   = (const float*)d_in[6];
    const float* u_c1_w    = (const float*)d_in[7];
    const float* u_c1_b    = (const float*)d_in[8];
    const float* u_c2_w    = (const float*)d_in[9];
    const float* u_c2_b    = (const float*)d_in[10];
    const float* ul_c1_w   = (const float*)d_in[11];
    const float* ul_c1_b   = (const float*)d_in[12];
    const float* ul_nin_w  = (const float*)d_in[13];
    const float* ul_nin_b  = (const float*)d_in[14];
    const float* ul_c2_w   = (const float*)d_in[15];
    const float* ul_c2_b   = (const float*)d_in[16];
    const float* nin_out_w = (const float*)d_in[17];
    const float* nin_out_b = (const float*)d_in[18];
    float* out = (float*)d_out;

    const size_t NU = (size_t)BZ * FCH * 1024;  // 5,242,880
    float* u  = (float*)d_ws;                    // [b][pix][160]
    float* ul = u + NU;
    unsigned short* CEu    = (unsigned short*)(ul + NU);   // [b][pix][320]
    unsigned short* CEc1u  = CEu + 2 * NU;
    unsigned short* CEc1ul = CEc1u + 2 * NU;
    unsigned short* CEul   = CEc1ul + 2 * NU;
    unsigned short* WBu1  = CEul + 2 * NU;
    unsigned short* WBu2  = WBu1 + (size_t)5 * 160 * 6 * 320;
    unsigned short* WBul1 = WBu2 + (size_t)5 * 320 * 6 * 320;
    unsigned short* WBnin = WBul1 + (size_t)5 * 160 * 4 * 320;
    unsigned short* WBul2 = WBnin + (size_t)5 * 160 * 1 * 320;
    unsigned short* WBnout = WBul2 + (size_t)5 * 320 * 4 * 320;
    float* partials = (float*)(WBnout + (size_t)128 * 160);   // 2048 floats
    float* zguard = partials + 2048;                          // 2KB zeros
    float* params = (float*)CEc1u;  // CEc1u dead once ninout runs

    dim3 blk(256);

    // LDS footprints (bytes) per conv variant
    const int SH_UC1  = (5 * 64 * 32 + 6 * 32 * 32) * 2;   // 32768
    const int SH_UC2  = (5 * 64 * 32 + 6 * 64 * 32) * 2;   // 45056
    const int SH_ULC1 = (5 * 64 * 32 + 4 * 32 * 32) * 2;   // 28672
    const int SH_ULC2 = (5 * 64 * 32 + 4 * 64 * 32) * 2;   // 36864
    const int SH_F1 = SH_UC1;   // max(28672, 32768)
    const int SH_F2 = SH_UC2;   // max(36864, 45056)

    // coalesced LDS-transpose repacks: grid = (CoutPad, NB)
    repack_k<<<dim3(160, 5), blk, 0, stream>>>(u_c1_w,    WBu1,  160, 320, 6, 1);
    repack_k<<<dim3(320, 5), blk, 0, stream>>>(u_c2_w,    WBu2,  320, 320, 6, 1);
    repack_k<<<dim3(160, 5), blk, 0, stream>>>(ul_c1_w,   WBul1, 160, 320, 4, 1);
    repack_k<<<dim3(160, 5), blk, 0, stream>>>(ul_nin_w,  WBnin, 160, 320, 1, 1);
    repack_k<<<dim3(320, 5), blk, 0, stream>>>(ul_c2_w,   WBul2, 320, 320, 4, 1);
    repack_k<<<dim3(128, 1), blk, 0, stream>>>(nin_out_w, WBnout, 100, 160, 1, 0);

    init_both_k<<<dim3(32, 32), blk, 0, stream>>>(
        samples, w_u_init, b_u_init, w_ul_d, b_ul_d, w_ul_dr, b_ul_dr,
        u, ul, CEu, CEul, zguard);

    const unsigned short* zg = (const unsigned short*)zguard;

    // u_c1(0), u_c2(0)
    conv_single_k<2, 3, 1, 1, false, false, 32><<<640, blk, SH_UC1, stream>>>(
        CEu, WBu1, nullptr, nullptr, u_c1_b, nullptr, nullptr, CEc1u, zg);
    conv_single_k<2, 3, 1, 1, false, true, 64><<<640, blk, SH_UC2, stream>>>(
        CEc1u, WBu2, nullptr, nullptr, u_c2_b, nullptr, u, CEu, zg);

    // steady state: {ul_c1(t) || u_c1(t+1)}, {ul_c2(t) || u_c2(t+1)}
    for (int t = 0; t < 4; ++t) {
        conv_fused_c1_k<<<1280, blk, SH_F1, stream>>>(
            CEul, WBul1 + (size_t)t * 160 * 4 * 320,
            CEu, WBnin + (size_t)t * 160 * 320,
            ul_c1_b + t * 160, ul_nin_b + t * 160, CEc1ul,
            CEu, WBu1 + (size_t)(t + 1) * 160 * 6 * 320,
            u_c1_b + (t + 1) * 160, CEc1u, zg);
        conv_fused_c2_k<<<1280, blk, SH_F2, stream>>>(
            CEc1ul, WBul2 + (size_t)t * 320 * 4 * 320,
            ul_c2_b + t * 320, ul, CEul,
            CEc1u, WBu2 + (size_t)(t + 1) * 320 * 6 * 320,
            u_c2_b + (t + 1) * 320, u, CEu, zg);
    }

    // tail: ul_c1(4), ul_c2(4)
    conv_single_k<2, 2, 1, 1, true, false, 32><<<640, blk, SH_ULC1, stream>>>(
        CEul, WBul1 + (size_t)4 * 160 * 4 * 320, CEu, WBnin + (size_t)4 * 160 * 320,
        ul_c1_b + 4 * 160, ul_nin_b + 4 * 160, nullptr, CEc1ul, zg);
    conv_single_k<2, 2, 1, 1, false, true, 64><<<640, blk, SH_ULC2, stream>>>(
        CEc1ul, WBul2 + (size_t)4 * 320 * 4 * 320, nullptr, nullptr,
        ul_c2_b + 4 * 320, nullptr, ul, CEul, zg);

    ninout_k<<<dim3(4, 128), blk, 0, stream>>>(ul, WBnout, nin_out_b, params);
    dmll_k<<<2048, blk, 0, stream>>>(samples, params, partials);
    dmll_final_k<<<1, 256, 0, stream>>>(partials, out);
}